// Round 4
// baseline (652.382 us; speedup 1.0000x reference)
//
#include <hip/hip_runtime.h>
#include <math.h>

#define S_N 2048
#define X_N 2048
#define G_N 2
#define F_N 3072

#define TM 128
#define TN 128
#define BK 32
#define ITERS (F_N / BK)  // 96

typedef __bf16 bf16;
typedef __bf16 bf16x4 __attribute__((ext_vector_type(4)));
typedef __bf16 bf16x8 __attribute__((ext_vector_type(8)));
typedef float f32x4 __attribute__((ext_vector_type(4)));

// s_waitcnt imm: vmcnt=63 ([3:0]=0xF,[15:14]=3), expcnt=7 ([6:4]), lgkmcnt=0 ([11:8])
#define WAIT_LGKM0() __builtin_amdgcn_s_waitcnt(0xc07f)

// ---------------- P0a: const[g] = -0.5*F*log(2pi) - sum_f log(std[g,f]) ----
__global__ void k_const(const float* __restrict__ stdv, float* __restrict__ constg) {
  int g = blockIdx.x;
  int t = threadIdx.x;
  float s = 0.f;
  for (int f = t; f < F_N; f += 256) s += logf(stdv[g * F_N + f]);
  for (int o = 32; o; o >>= 1) s += __shfl_xor(s, o);
  __shared__ float red[4];
  int w = t >> 6, l = t & 63;
  if (l == 0) red[w] = s;
  __syncthreads();
  if (t == 0) {
    float tot = red[0] + red[1] + red[2] + red[3];
    constg[g] = -0.5f * (float)F_N * 1.8378770664093453f - tot;
  }
}

// ---------------- P0b: u = s/std_g (bf16) + A[g,s]=||u||^2 ; same for x->v,C
__global__ void k_prep(const float* __restrict__ samples, const float* __restrict__ xin,
                       const float* __restrict__ stdv,
                       bf16* __restrict__ U, bf16* __restrict__ V,
                       float* __restrict__ A, float* __restrict__ C) {
  int r = blockIdx.x;
  int t = threadIdx.x;
  bool isS = (r < S_N);
  const float* src = isS ? (samples + (size_t)r * F_N) : (xin + (size_t)(r - S_N) * F_N);
  float4 row[3];
#pragma unroll
  for (int j = 0; j < 3; ++j) row[j] = ((const float4*)src)[t + j * 256];

  __shared__ float red[4];
  int w = t >> 6, l = t & 63;

  for (int g = 0; g < G_N; ++g) {
    const float4* sd = (const float4*)(stdv + (size_t)g * F_N);
    bf16* dst = isS ? (U + ((size_t)g * S_N + r) * F_N)
                    : (V + ((size_t)g * X_N + (r - S_N)) * F_N);
    float acc = 0.f;
#pragma unroll
    for (int j = 0; j < 3; ++j) {
      float4 d = sd[t + j * 256];
      float u0 = row[j].x / d.x;
      float u1 = row[j].y / d.y;
      float u2 = row[j].z / d.z;
      float u3 = row[j].w / d.w;
      bf16x4 b;
      b[0] = (bf16)u0; b[1] = (bf16)u1; b[2] = (bf16)u2; b[3] = (bf16)u3;
      float f0 = (float)b[0], f1 = (float)b[1], f2 = (float)b[2], f3 = (float)b[3];
      acc += f0 * f0 + f1 * f1 + f2 * f2 + f3 * f3;
      ((bf16x4*)dst)[t + j * 256] = b;
    }
    for (int o = 32; o; o >>= 1) acc += __shfl_xor(acc, o);
    __syncthreads();
    if (l == 0) red[w] = acc;
    __syncthreads();
    if (t == 0) {
      float tot = red[0] + red[1] + red[2] + red[3];
      if (isS) A[(size_t)g * S_N + r] = tot;
      else     C[(size_t)g * X_N + (r - S_N)] = tot;
    }
  }
}

// ---------------- P1: logits[g,s,x] = (u v^T)[s,x] - 0.5*(A[g,s]+C[g,x]) ----
// 128x128 tile, 256 thr (2x2 waves of 64x64). 3-stage pipeline:
//   iter it: issue global->VGPR loads for tile it+2; MFMA on tile it from
//   lds[it%2]; ds_write tile it+1 (regs, loaded last iter) to lds[(it+1)%2];
//   lgkm-only wait + raw s_barrier (prefetch loads stay in flight across it).
// Last 2 prefetches read in-workspace garbage that is never consumed.
__global__ __launch_bounds__(256) void k_gemm(const bf16* __restrict__ U, const bf16* __restrict__ V,
                                              const float* __restrict__ A, const float* __restrict__ C,
                                              float* __restrict__ logits) {
  __shared__ bf16 ldsA[2][TM * BK];
  __shared__ bf16 ldsB[2][TN * BK];

  int t = threadIdx.x;
  int g = blockIdx.z;
  int bm = blockIdx.y * TM;
  int bn = blockIdx.x * TN;

  const bf16* Ub = U + ((size_t)g * S_N + bm) * F_N;
  const bf16* Vb = V + ((size_t)g * X_N + bn) * F_N;

  int wave = t >> 6, lane = t & 63;
  int wm = wave & 1, wn = wave >> 1;   // 2x2 waves, 64x64 each
  int r = lane & 15, q = lane >> 4;
  int sq = q ^ ((r >> 1) & 3);         // conflict-free read swizzle (R3-verified)

  // Staging: 512 16B chunks per tile; thread t owns chunks c0=t, c1=t+256.
  // LDS slot (row, cc) holds global chunk (row, cc ^ ((row>>1)&3)).
  int c0 = t, c1 = t + 256;
  int row0 = c0 >> 2, gc0 = (c0 & 3) ^ ((row0 >> 1) & 3);
  int row1 = c1 >> 2, gc1 = (c1 & 3) ^ ((row1 >> 1) & 3);
  const bf16* gA0 = Ub + (size_t)row0 * F_N + gc0 * 8;
  const bf16* gA1 = Ub + (size_t)row1 * F_N + gc1 * 8;
  const bf16* gB0 = Vb + (size_t)row0 * F_N + gc0 * 8;
  const bf16* gB1 = Vb + (size_t)row1 * F_N + gc1 * 8;

  f32x4 acc[4][4] = {};
  int abase = (wm * 64 + r) * BK + sq * 8;
  int bbase = (wn * 64 + r) * BK + sq * 8;

  // register staging buffers: slot T%2 holds tile T
  bf16x8 sA0[2], sA1[2], sB0[2], sB1[2];

  // prologue: tile 0 and tile 1 into regs; tile 0 -> lds[0]
  sA0[0] = *(const bf16x8*)(gA0);      sA1[0] = *(const bf16x8*)(gA1);
  sB0[0] = *(const bf16x8*)(gB0);      sB1[0] = *(const bf16x8*)(gB1);
  sA0[1] = *(const bf16x8*)(gA0 + BK); sA1[1] = *(const bf16x8*)(gA1 + BK);
  sB0[1] = *(const bf16x8*)(gB0 + BK); sB1[1] = *(const bf16x8*)(gB1 + BK);
  *(bf16x8*)(&ldsA[0][c0 * 8]) = sA0[0];
  *(bf16x8*)(&ldsA[0][c1 * 8]) = sA1[0];
  *(bf16x8*)(&ldsB[0][c0 * 8]) = sB0[0];
  *(bf16x8*)(&ldsB[0][c1 * 8]) = sB1[0];
  WAIT_LGKM0();
  __builtin_amdgcn_s_barrier();

  for (int it = 0; it < ITERS; ++it) {
    int b = it & 1, nb = b ^ 1;
    int pk = (it + 2) * BK;  // prefetch tile it+2 into slot b (tile it's regs, consumed)
    sA0[b] = *(const bf16x8*)(gA0 + pk);
    sA1[b] = *(const bf16x8*)(gA1 + pk);
    sB0[b] = *(const bf16x8*)(gB0 + pk);
    sB1[b] = *(const bf16x8*)(gB1 + pk);

    bf16x8 af[4], bfr[4];
#pragma unroll
    for (int mi = 0; mi < 4; ++mi) af[mi] = *(const bf16x8*)(&ldsA[b][abase + mi * 16 * BK]);
#pragma unroll
    for (int ni = 0; ni < 4; ++ni) bfr[ni] = *(const bf16x8*)(&ldsB[b][bbase + ni * 16 * BK]);

#pragma unroll
    for (int mi = 0; mi < 4; ++mi)
#pragma unroll
      for (int ni = 0; ni < 4; ++ni)
        acc[mi][ni] = __builtin_amdgcn_mfma_f32_16x16x32_bf16(af[mi], bfr[ni], acc[mi][ni], 0, 0, 0);

    // write tile it+1 (regs slot nb, loaded one full iteration ago) to lds[nb]
    *(bf16x8*)(&ldsA[nb][c0 * 8]) = sA0[nb];
    *(bf16x8*)(&ldsA[nb][c1 * 8]) = sA1[nb];
    *(bf16x8*)(&ldsB[nb][c0 * 8]) = sB0[nb];
    *(bf16x8*)(&ldsB[nb][c1 * 8]) = sB1[nb];

    WAIT_LGKM0();                     // ds ops drained; prefetch vmem stays in flight
    __builtin_amdgcn_s_barrier();
  }

  // Epilogue: C/D layout col=lane&15, row=(lane>>4)*4+reg
  const float* Ap = A + (size_t)g * S_N + bm + wm * 64;
  const float* Cp = C + (size_t)g * X_N + bn + wn * 64;
  float cv[4];
#pragma unroll
  for (int ni = 0; ni < 4; ++ni) cv[ni] = Cp[ni * 16 + r];
#pragma unroll
  for (int mi = 0; mi < 4; ++mi) {
#pragma unroll
    for (int i = 0; i < 4; ++i) {
      int rowl = wm * 64 + mi * 16 + q * 4 + i;
      float av = Ap[mi * 16 + q * 4 + i];
      float* orow = logits + ((size_t)g * S_N + bm + rowl) * X_N + bn + wn * 64;
#pragma unroll
      for (int ni = 0; ni < 4; ++ni)
        orow[ni * 16 + r] = acc[mi][ni][i] - 0.5f * (av + cv[ni]);
    }
  }
}

// ---------------- P2: out[s] = LSE over (g,x) of (logits + const[g]) - log(X*G)
__global__ void k_lse(const float* __restrict__ logits, const float* __restrict__ constg,
                      float* __restrict__ out) {
  int s = blockIdx.x, t = threadIdx.x;
  float c0 = constg[0], c1 = constg[1];
  const float4* p0 = (const float4*)(logits + (size_t)s * X_N);
  const float4* p1 = (const float4*)(logits + ((size_t)S_N + s) * X_N);
  float4 v[4];
  v[0] = p0[t]; v[1] = p0[t + 256];
  v[2] = p1[t]; v[3] = p1[t + 256];
  v[0].x += c0; v[0].y += c0; v[0].z += c0; v[0].w += c0;
  v[1].x += c0; v[1].y += c0; v[1].z += c0; v[1].w += c0;
  v[2].x += c1; v[2].y += c1; v[2].z += c1; v[2].w += c1;
  v[3].x += c1; v[3].y += c1; v[3].z += c1; v[3].w += c1;

  float m = v[0].x;
#pragma unroll
  for (int j = 0; j < 4; ++j) {
    m = fmaxf(m, v[j].x); m = fmaxf(m, v[j].y);
    m = fmaxf(m, v[j].z); m = fmaxf(m, v[j].w);
  }
  for (int o = 32; o; o >>= 1) m = fmaxf(m, __shfl_xor(m, o));
  __shared__ float redm[4];
  __shared__ float reds[4];
  int w = t >> 6, l = t & 63;
  if (l == 0) redm[w] = m;
  __syncthreads();
  m = fmaxf(fmaxf(redm[0], redm[1]), fmaxf(redm[2], redm[3]));

  float sum = 0.f;
#pragma unroll
  for (int j = 0; j < 4; ++j) {
    sum += expf(v[j].x - m) + expf(v[j].y - m) + expf(v[j].z - m) + expf(v[j].w - m);
  }
  for (int o = 32; o; o >>= 1) sum += __shfl_xor(sum, o);
  if (l == 0) reds[w] = sum;
  __syncthreads();
  if (t == 0) {
    float tot = reds[0] + reds[1] + reds[2] + reds[3];
    out[s] = m + logf(tot) - 8.317766166719343f;  // log(4096)
  }
}

extern "C" void kernel_launch(void* const* d_in, const int* in_sizes, int n_in,
                              void* d_out, int out_size, void* d_ws, size_t ws_size,
                              hipStream_t stream) {
  const float* samples = (const float*)d_in[0];  // [S, F] fp32
  const float* xin     = (const float*)d_in[1];  // [X, F] fp32
  const float* stdv    = (const float*)d_in[2];  // [G, F] fp32
  float* out = (float*)d_out;                    // [S] fp32

  char* ws = (char*)d_ws;
  size_t off = 0;
  bf16* U = (bf16*)(ws + off);        off += (size_t)G_N * S_N * F_N * 2;  // 25.2 MB
  bf16* V = (bf16*)(ws + off);        off += (size_t)G_N * X_N * F_N * 2;  // 25.2 MB
  float* logits = (float*)(ws + off); off += (size_t)G_N * S_N * X_N * 4;  // 33.6 MB (also absorbs prefetch overreach)
  float* A = (float*)(ws + off);      off += (size_t)G_N * S_N * 4;
  float* C = (float*)(ws + off);      off += (size_t)G_N * X_N * 4;
  float* constg = (float*)(ws + off); off += 256;

  k_const<<<dim3(G_N), dim3(256), 0, stream>>>(stdv, constg);
  k_prep<<<dim3(S_N + X_N), dim3(256), 0, stream>>>(samples, xin, stdv, U, V, A, C);
  k_gemm<<<dim3(X_N / TN, S_N / TM, G_N), dim3(256), 0, stream>>>(U, V, A, C, logits);
  k_lse<<<dim3(S_N), dim3(256), 0, stream>>>(logits, constg, out);
}

// Round 6
// 172.808 us; speedup vs baseline: 3.7752x; 3.7752x over previous
//
#include <hip/hip_runtime.h>
#include <math.h>

#define S_N 2048
#define X_N 2048
#define G_N 2
#define F_N 3072

#define TM 128
#define TN 128
#define BK 32
#define ITERS (F_N / BK)  // 96

typedef __bf16 bf16;
typedef __bf16 bf16x4 __attribute__((ext_vector_type(4)));
typedef __bf16 bf16x8 __attribute__((ext_vector_type(8)));
typedef float f32x4 __attribute__((ext_vector_type(4)));
typedef int i32x4 __attribute__((ext_vector_type(4)));

// lgkm-only drain + barrier; memory clobber pins DS ordering, vmcnt stays in flight
#define LGKM_BARRIER() asm volatile("s_waitcnt lgkmcnt(0)\n\ts_barrier" ::: "memory")

// ---------------- P0a: const[g] = -0.5*F*log(2pi) - sum_f log(std[g,f]) ----
__global__ void k_const(const float* __restrict__ stdv, float* __restrict__ constg) {
  int g = blockIdx.x;
  int t = threadIdx.x;
  float s = 0.f;
  for (int f = t; f < F_N; f += 256) s += logf(stdv[g * F_N + f]);
  for (int o = 32; o; o >>= 1) s += __shfl_xor(s, o);
  __shared__ float red[4];
  int w = t >> 6, l = t & 63;
  if (l == 0) red[w] = s;
  __syncthreads();
  if (t == 0) {
    float tot = red[0] + red[1] + red[2] + red[3];
    constg[g] = -0.5f * (float)F_N * 1.8378770664093453f - tot;
  }
}

// ---------------- P0b: u = s/std_g (bf16) + A[g,s]=||u||^2 ; same for x->v,C
__global__ void k_prep(const float* __restrict__ samples, const float* __restrict__ xin,
                       const float* __restrict__ stdv,
                       bf16* __restrict__ U, bf16* __restrict__ V,
                       float* __restrict__ A, float* __restrict__ C) {
  int r = blockIdx.x;
  int t = threadIdx.x;
  bool isS = (r < S_N);
  const float* src = isS ? (samples + (size_t)r * F_N) : (xin + (size_t)(r - S_N) * F_N);
  float4 row[3];
#pragma unroll
  for (int j = 0; j < 3; ++j) row[j] = ((const float4*)src)[t + j * 256];

  __shared__ float red[4];
  int w = t >> 6, l = t & 63;

  for (int g = 0; g < G_N; ++g) {
    const float4* sd = (const float4*)(stdv + (size_t)g * F_N);
    bf16* dst = isS ? (U + ((size_t)g * S_N + r) * F_N)
                    : (V + ((size_t)g * X_N + (r - S_N)) * F_N);
    float acc = 0.f;
#pragma unroll
    for (int j = 0; j < 3; ++j) {
      float4 d = sd[t + j * 256];
      float u0 = row[j].x / d.x;
      float u1 = row[j].y / d.y;
      float u2 = row[j].z / d.z;
      float u3 = row[j].w / d.w;
      bf16x4 b;
      b[0] = (bf16)u0; b[1] = (bf16)u1; b[2] = (bf16)u2; b[3] = (bf16)u3;
      float f0 = (float)b[0], f1 = (float)b[1], f2 = (float)b[2], f3 = (float)b[3];
      acc += f0 * f0 + f1 * f1 + f2 * f2 + f3 * f3;
      ((bf16x4*)dst)[t + j * 256] = b;
    }
    for (int o = 32; o; o >>= 1) acc += __shfl_xor(acc, o);
    __syncthreads();
    if (l == 0) red[w] = acc;
    __syncthreads();
    if (t == 0) {
      float tot = red[0] + red[1] + red[2] + red[3];
      if (isS) A[(size_t)g * S_N + r] = tot;
      else     C[(size_t)g * X_N + (r - S_N)] = tot;
    }
  }
}

// ---------------- P1: logits[g,s,x] = (u v^T)[s,x] - 0.5*(A[g,s]+C[g,s]) ----
// 128x128 tile, 256 thr (2x2 waves of 64x64). 3-stage pipeline, unrolled x2
// (double-buffer index compile-time; staging slots are named i32x4 registers).
// Per phase: global->reg prefetch tile it+2; MFMA tile it from lds; ds_write
// tile it+1 regs -> other lds buf; lgkm-only barrier (vmem stays in flight).
// All LDS traffic is i32x4-typed (no TBAA mixing); bit_cast at MFMA operand.
__global__ __launch_bounds__(256) void k_gemm(const bf16* __restrict__ U, const bf16* __restrict__ V,
                                              const float* __restrict__ A, const float* __restrict__ C,
                                              float* __restrict__ logits) {
  __shared__ i32x4 ldsA[2][TM * BK / 8];  // 512 chunks of 16B per buf
  __shared__ i32x4 ldsB[2][TN * BK / 8];

  int t = threadIdx.x;
  int g = blockIdx.z;
  int bm = blockIdx.y * TM;
  int bn = blockIdx.x * TN;

  const bf16* Ub = U + ((size_t)g * S_N + bm) * F_N;
  const bf16* Vb = V + ((size_t)g * X_N + bn) * F_N;

  int wave = t >> 6, lane = t & 63;
  int wm = wave & 1, wn = wave >> 1;   // 2x2 waves, 64x64 each
  int r = lane & 15, q = lane >> 4;
  int sq = q ^ ((r >> 1) & 3);         // conflict-free read swizzle (R3-verified)

  // Staging: 512 16B chunks per tile; thread t owns chunks c0=t, c1=t+256.
  // LDS slot (row, cc) holds global chunk (row, cc ^ ((row>>1)&3)).
  int c0 = t, c1 = t + 256;
  int row0 = c0 >> 2, gc0 = (c0 & 3) ^ ((row0 >> 1) & 3);
  int row1 = c1 >> 2, gc1 = (c1 & 3) ^ ((row1 >> 1) & 3);
  const bf16* gA0 = Ub + (size_t)row0 * F_N + gc0 * 8;
  const bf16* gA1 = Ub + (size_t)row1 * F_N + gc1 * 8;
  const bf16* gB0 = Vb + (size_t)row0 * F_N + gc0 * 8;
  const bf16* gB1 = Vb + (size_t)row1 * F_N + gc1 * 8;

  f32x4 acc[4][4] = {};
  // i32x4-granular LDS read indices
  int abase = (wm * 64 + r) * 4 + sq;
  int bbase = (wn * 64 + r) * 4 + sq;

  // named staging registers: slot0 holds even tiles, slot1 odd tiles
  i32x4 a0_0, a1_0, b0_0, b1_0;
  i32x4 a0_1, a1_1, b0_1, b1_1;

  // prologue: tile 0 -> slot0, tile 1 -> slot1; slot0 -> lds[0]
  a0_0 = *(const i32x4*)(gA0);      a1_0 = *(const i32x4*)(gA1);
  b0_0 = *(const i32x4*)(gB0);      b1_0 = *(const i32x4*)(gB1);
  a0_1 = *(const i32x4*)(gA0 + BK); a1_1 = *(const i32x4*)(gA1 + BK);
  b0_1 = *(const i32x4*)(gB0 + BK); b1_1 = *(const i32x4*)(gB1 + BK);
  ldsA[0][c0] = a0_0;
  ldsA[0][c1] = a1_0;
  ldsB[0][c0] = b0_0;
  ldsB[0][c1] = b1_0;
  LGKM_BARRIER();

  for (int it = 0; it < ITERS; it += 2) {
    // ---- phase 0: compute tile it from lds[0]; prefetch it+2 -> slot0;
    //      ds_write slot1 (tile it+1, loaded a full iter ago) -> lds[1]
    {
      int k2 = it + 2;
      int pk = (k2 < ITERS ? k2 : 0) * BK;  // clamped: always in-bounds
      a0_0 = *(const i32x4*)(gA0 + pk);
      a1_0 = *(const i32x4*)(gA1 + pk);
      b0_0 = *(const i32x4*)(gB0 + pk);
      b1_0 = *(const i32x4*)(gB1 + pk);

      bf16x8 af[4], bfr[4];
#pragma unroll
      for (int mi = 0; mi < 4; ++mi)
        af[mi] = __builtin_bit_cast(bf16x8, ldsA[0][abase + mi * 64]);
#pragma unroll
      for (int ni = 0; ni < 4; ++ni)
        bfr[ni] = __builtin_bit_cast(bf16x8, ldsB[0][bbase + ni * 64]);
#pragma unroll
      for (int mi = 0; mi < 4; ++mi)
#pragma unroll
        for (int ni = 0; ni < 4; ++ni)
          acc[mi][ni] = __builtin_amdgcn_mfma_f32_16x16x32_bf16(af[mi], bfr[ni], acc[mi][ni], 0, 0, 0);

      ldsA[1][c0] = a0_1;
      ldsA[1][c1] = a1_1;
      ldsB[1][c0] = b0_1;
      ldsB[1][c1] = b1_1;
      LGKM_BARRIER();
    }
    // ---- phase 1: compute tile it+1 from lds[1]; prefetch it+3 -> slot1;
    //      ds_write slot0 (tile it+2) -> lds[0]
    {
      int k3 = it + 3;
      int pk = (k3 < ITERS ? k3 : 0) * BK;
      a0_1 = *(const i32x4*)(gA0 + pk);
      a1_1 = *(const i32x4*)(gA1 + pk);
      b0_1 = *(const i32x4*)(gB0 + pk);
      b1_1 = *(const i32x4*)(gB1 + pk);

      bf16x8 af[4], bfr[4];
#pragma unroll
      for (int mi = 0; mi < 4; ++mi)
        af[mi] = __builtin_bit_cast(bf16x8, ldsA[1][abase + mi * 64]);
#pragma unroll
      for (int ni = 0; ni < 4; ++ni)
        bfr[ni] = __builtin_bit_cast(bf16x8, ldsB[1][bbase + ni * 64]);
#pragma unroll
      for (int mi = 0; mi < 4; ++mi)
#pragma unroll
        for (int ni = 0; ni < 4; ++ni)
          acc[mi][ni] = __builtin_amdgcn_mfma_f32_16x16x32_bf16(af[mi], bfr[ni], acc[mi][ni], 0, 0, 0);

      ldsA[0][c0] = a0_0;
      ldsA[0][c1] = a1_0;
      ldsB[0][c0] = b0_0;
      ldsB[0][c1] = b1_0;
      LGKM_BARRIER();
    }
  }

  // Epilogue: C/D layout col=lane&15, row=(lane>>4)*4+reg
  const float* Ap = A + (size_t)g * S_N + bm + wm * 64;
  const float* Cp = C + (size_t)g * X_N + bn + wn * 64;
  float cv[4];
#pragma unroll
  for (int ni = 0; ni < 4; ++ni) cv[ni] = Cp[ni * 16 + r];
#pragma unroll
  for (int mi = 0; mi < 4; ++mi) {
#pragma unroll
    for (int i = 0; i < 4; ++i) {
      int rowl = wm * 64 + mi * 16 + q * 4 + i;
      float av = Ap[mi * 16 + q * 4 + i];
      float* orow = logits + ((size_t)g * S_N + bm + rowl) * X_N + bn + wn * 64;
#pragma unroll
      for (int ni = 0; ni < 4; ++ni)
        orow[ni * 16 + r] = acc[mi][ni][i] - 0.5f * (av + cv[ni]);
    }
  }
}

// ---------------- P2: out[s] = LSE over (g,x) of (logits + const[g]) - log(X*G)
__global__ void k_lse(const float* __restrict__ logits, const float* __restrict__ constg,
                      float* __restrict__ out) {
  int s = blockIdx.x, t = threadIdx.x;
  float c0 = constg[0], c1 = constg[1];
  const float4* p0 = (const float4*)(logits + (size_t)s * X_N);
  const float4* p1 = (const float4*)(logits + ((size_t)S_N + s) * X_N);
  float4 v[4];
  v[0] = p0[t]; v[1] = p0[t + 256];
  v[2] = p1[t]; v[3] = p1[t + 256];
  v[0].x += c0; v[0].y += c0; v[0].z += c0; v[0].w += c0;
  v[1].x += c0; v[1].y += c0; v[1].z += c0; v[1].w += c0;
  v[2].x += c1; v[2].y += c1; v[2].z += c1; v[2].w += c1;
  v[3].x += c1; v[3].y += c1; v[3].z += c1; v[3].w += c1;

  float m = v[0].x;
#pragma unroll
  for (int j = 0; j < 4; ++j) {
    m = fmaxf(m, v[j].x); m = fmaxf(m, v[j].y);
    m = fmaxf(m, v[j].z); m = fmaxf(m, v[j].w);
  }
  for (int o = 32; o; o >>= 1) m = fmaxf(m, __shfl_xor(m, o));
  __shared__ float redm[4];
  __shared__ float reds[4];
  int w = t >> 6, l = t & 63;
  if (l == 0) redm[w] = m;
  __syncthreads();
  m = fmaxf(fmaxf(redm[0], redm[1]), fmaxf(redm[2], redm[3]));

  float sum = 0.f;
#pragma unroll
  for (int j = 0; j < 4; ++j) {
    sum += expf(v[j].x - m) + expf(v[j].y - m) + expf(v[j].z - m) + expf(v[j].w - m);
  }
  for (int o = 32; o; o >>= 1) sum += __shfl_xor(sum, o);
  if (l == 0) reds[w] = sum;
  __syncthreads();
  if (t == 0) {
    float tot = reds[0] + reds[1] + reds[2] + reds[3];
    out[s] = m + logf(tot) - 8.317766166719343f;  // log(4096)
  }
}

extern "C" void kernel_launch(void* const* d_in, const int* in_sizes, int n_in,
                              void* d_out, int out_size, void* d_ws, size_t ws_size,
                              hipStream_t stream) {
  const float* samples = (const float*)d_in[0];  // [S, F] fp32
  const float* xin     = (const float*)d_in[1];  // [X, F] fp32
  const float* stdv    = (const float*)d_in[2];  // [G, F] fp32
  float* out = (float*)d_out;                    // [S] fp32

  char* ws = (char*)d_ws;
  size_t off = 0;
  bf16* U = (bf16*)(ws + off);        off += (size_t)G_N * S_N * F_N * 2;  // 25.2 MB
  bf16* V = (bf16*)(ws + off);        off += (size_t)G_N * X_N * F_N * 2;  // 25.2 MB
  float* logits = (float*)(ws + off); off += (size_t)G_N * S_N * X_N * 4;  // 33.6 MB
  float* A = (float*)(ws + off);      off += (size_t)G_N * S_N * 4;
  float* C = (float*)(ws + off);      off += (size_t)G_N * X_N * 4;
  float* constg = (float*)(ws + off); off += 256;

  k_const<<<dim3(G_N), dim3(256), 0, stream>>>(stdv, constg);
  k_prep<<<dim3(S_N + X_N), dim3(256), 0, stream>>>(samples, xin, stdv, U, V, A, C);
  k_gemm<<<dim3(X_N / TN, S_N / TM, G_N), dim3(256), 0, stream>>>(U, V, A, C, logits);
  k_lse<<<dim3(S_N), dim3(256), 0, stream>>>(logits, constg, out);
}

// Round 7
// 162.902 us; speedup vs baseline: 4.0047x; 1.0608x over previous
//
#include <hip/hip_runtime.h>
#include <math.h>

#define S_N 2048
#define X_N 2048
#define G_N 2
#define F_N 3072

#define TM 128
#define TN 128
#define BK 64
#define ITERS (F_N / BK)  // 48

typedef __bf16 bf16;
typedef __bf16 bf16x4 __attribute__((ext_vector_type(4)));
typedef __bf16 bf16x8 __attribute__((ext_vector_type(8)));
typedef float f32x4 __attribute__((ext_vector_type(4)));
typedef int i32x4 __attribute__((ext_vector_type(4)));

// lgkm-only drain + barrier; memory clobber pins DS ordering, vmcnt stays in flight
#define LGKM_BARRIER() asm volatile("s_waitcnt lgkmcnt(0)\n\ts_barrier" ::: "memory")

// ---------------- P0a: const[g] + rinv[g,f] = 1/std ----
__global__ void k_const(const float* __restrict__ stdv, float* __restrict__ constg,
                        float* __restrict__ rinv) {
  int g = blockIdx.x;
  int t = threadIdx.x;
  float s = 0.f;
  for (int f = t; f < F_N; f += 256) {
    float v = stdv[g * F_N + f];
    rinv[g * F_N + f] = 1.0f / v;
    s += logf(v);
  }
  for (int o = 32; o; o >>= 1) s += __shfl_xor(s, o);
  __shared__ float red[4];
  int w = t >> 6, l = t & 63;
  if (l == 0) red[w] = s;
  __syncthreads();
  if (t == 0) {
    float tot = red[0] + red[1] + red[2] + red[3];
    constg[g] = -0.5f * (float)F_N * 1.8378770664093453f - tot;
  }
}

// ---------------- P0b: u = s*rinv_g (bf16) + A[g,s]=||u||^2 ; same for x->v,C
__global__ void k_prep(const float* __restrict__ samples, const float* __restrict__ xin,
                       const float* __restrict__ rinv,
                       bf16* __restrict__ U, bf16* __restrict__ V,
                       float* __restrict__ A, float* __restrict__ C) {
  int r = blockIdx.x;
  int t = threadIdx.x;
  bool isS = (r < S_N);
  const float* src = isS ? (samples + (size_t)r * F_N) : (xin + (size_t)(r - S_N) * F_N);
  float4 row[3];
#pragma unroll
  for (int j = 0; j < 3; ++j) row[j] = ((const float4*)src)[t + j * 256];

  __shared__ float red[4];
  int w = t >> 6, l = t & 63;

  for (int g = 0; g < G_N; ++g) {
    const float4* sd = (const float4*)(rinv + (size_t)g * F_N);
    bf16* dst = isS ? (U + ((size_t)g * S_N + r) * F_N)
                    : (V + ((size_t)g * X_N + (r - S_N)) * F_N);
    float acc = 0.f;
#pragma unroll
    for (int j = 0; j < 3; ++j) {
      float4 d = sd[t + j * 256];
      float u0 = row[j].x * d.x;
      float u1 = row[j].y * d.y;
      float u2 = row[j].z * d.z;
      float u3 = row[j].w * d.w;
      bf16x4 b;
      b[0] = (bf16)u0; b[1] = (bf16)u1; b[2] = (bf16)u2; b[3] = (bf16)u3;
      float f0 = (float)b[0], f1 = (float)b[1], f2 = (float)b[2], f3 = (float)b[3];
      acc += f0 * f0 + f1 * f1 + f2 * f2 + f3 * f3;
      ((bf16x4*)dst)[t + j * 256] = b;
    }
    for (int o = 32; o; o >>= 1) acc += __shfl_xor(acc, o);
    __syncthreads();
    if (l == 0) red[w] = acc;
    __syncthreads();
    if (t == 0) {
      float tot = red[0] + red[1] + red[2] + red[3];
      if (isS) A[(size_t)g * S_N + r] = tot;
      else     C[(size_t)g * X_N + (r - S_N)] = tot;
    }
  }
}

// ---------------- P1: logits[g,s,x] = (u v^T)[s,x] - 0.5*(A[g,s]+C[g,x]) ----
// 128x128 tile, BK=64 (48 iters), 256 thr (2x2 waves of 64x64). R6 register
// pipeline: per phase prefetch tile it+2 (8x i32x4 global->reg), 32 MFMA from
// lds[buf], ds_write tile it+1 regs->other buf, lgkm-only barrier.
// 3-bit XOR swizzle f(row)=(row>>1)&7: at 128B row stride every b128 read
// spreads over all 32 banks (8 lanes per 4-bank group = minimum).
__global__ __launch_bounds__(256, 2) void k_gemm(const bf16* __restrict__ U, const bf16* __restrict__ V,
                                                 const float* __restrict__ A, const float* __restrict__ C,
                                                 float* __restrict__ logits) {
  __shared__ i32x4 ldsA[2][TM * BK / 8];  // 1024 slots x 16B per buf
  __shared__ i32x4 ldsB[2][TN * BK / 8];

  int t = threadIdx.x;
  int g = blockIdx.z;
  int bm = blockIdx.y * TM;
  int bn = blockIdx.x * TN;

  const bf16* Ub = U + ((size_t)g * S_N + bm) * F_N;
  const bf16* Vb = V + ((size_t)g * X_N + bn) * F_N;

  int wave = t >> 6, lane = t & 63;
  int wm = wave & 1, wn = wave >> 1;   // 2x2 waves, 64x64 each
  int r = lane & 15, q = lane >> 4;
  int fr = (r >> 1) & 7;               // 3-bit read swizzle
  int ck0 = q ^ fr;                    // slot chunk for ks=0 (global chunk q)
  int ck1 = (4 | q) ^ fr;              // slot chunk for ks=1 (global chunk 4+q)

  // Staging: 1024 16B chunks per tile; thread t owns slots t+j*256, j=0..3.
  // LDS slot (row, cc) holds global chunk (row, cc ^ ((row>>1)&7)).
  // For slot t+j*256: row_j = (t>>3)+j*32, cc = t&7,
  // gcc = (t&7) ^ ((t>>4)&7)  (same for all j).
  int row0 = t >> 3;
  int gcc = (t & 7) ^ ((t >> 4) & 7);
  const bf16* gA[4];
  const bf16* gB[4];
#pragma unroll
  for (int j = 0; j < 4; ++j) {
    gA[j] = Ub + (size_t)(row0 + j * 32) * F_N + gcc * 8;
    gB[j] = Vb + (size_t)(row0 + j * 32) * F_N + gcc * 8;
  }

  f32x4 acc[4][4] = {};
  int abase = (wm * 64 + r) * 8;
  int bbase = (wn * 64 + r) * 8;

  // named staging slots: slot0 = even tiles, slot1 = odd tiles
  i32x4 sA0[4], sB0[4], sA1[4], sB1[4];

  // prologue: tile0 -> slot0, tile1 -> slot1; slot0 -> lds[0]
#pragma unroll
  for (int j = 0; j < 4; ++j) {
    sA0[j] = *(const i32x4*)(gA[j]);
    sB0[j] = *(const i32x4*)(gB[j]);
  }
#pragma unroll
  for (int j = 0; j < 4; ++j) {
    sA1[j] = *(const i32x4*)(gA[j] + BK);
    sB1[j] = *(const i32x4*)(gB[j] + BK);
  }
#pragma unroll
  for (int j = 0; j < 4; ++j) {
    ldsA[0][t + j * 256] = sA0[j];
    ldsB[0][t + j * 256] = sB0[j];
  }
  LGKM_BARRIER();

  for (int it = 0; it < ITERS; it += 2) {
    // ---- phase 0: compute tile it from lds[0]; prefetch it+2 -> slot0;
    //      ds_write slot1 (tile it+1) -> lds[1]
    {
      int k2 = it + 2;
      int pk = (k2 < ITERS ? k2 : 0) * BK;  // clamped: always in-bounds
#pragma unroll
      for (int j = 0; j < 4; ++j) {
        sA0[j] = *(const i32x4*)(gA[j] + pk);
        sB0[j] = *(const i32x4*)(gB[j] + pk);
      }
#pragma unroll
      for (int ks = 0; ks < 2; ++ks) {
        int ck = ks ? ck1 : ck0;
        bf16x8 af[4], bfr[4];
#pragma unroll
        for (int mi = 0; mi < 4; ++mi)
          af[mi] = __builtin_bit_cast(bf16x8, ldsA[0][abase + mi * 128 + ck]);
#pragma unroll
        for (int ni = 0; ni < 4; ++ni)
          bfr[ni] = __builtin_bit_cast(bf16x8, ldsB[0][bbase + ni * 128 + ck]);
#pragma unroll
        for (int mi = 0; mi < 4; ++mi)
#pragma unroll
          for (int ni = 0; ni < 4; ++ni)
            acc[mi][ni] = __builtin_amdgcn_mfma_f32_16x16x32_bf16(af[mi], bfr[ni], acc[mi][ni], 0, 0, 0);
      }
#pragma unroll
      for (int j = 0; j < 4; ++j) {
        ldsA[1][t + j * 256] = sA1[j];
        ldsB[1][t + j * 256] = sB1[j];
      }
      LGKM_BARRIER();
    }
    // ---- phase 1: compute tile it+1 from lds[1]; prefetch it+3 -> slot1;
    //      ds_write slot0 (tile it+2) -> lds[0]
    {
      int k3 = it + 3;
      int pk = (k3 < ITERS ? k3 : 0) * BK;
#pragma unroll
      for (int j = 0; j < 4; ++j) {
        sA1[j] = *(const i32x4*)(gA[j] + pk);
        sB1[j] = *(const i32x4*)(gB[j] + pk);
      }
#pragma unroll
      for (int ks = 0; ks < 2; ++ks) {
        int ck = ks ? ck1 : ck0;
        bf16x8 af[4], bfr[4];
#pragma unroll
        for (int mi = 0; mi < 4; ++mi)
          af[mi] = __builtin_bit_cast(bf16x8, ldsA[1][abase + mi * 128 + ck]);
#pragma unroll
        for (int ni = 0; ni < 4; ++ni)
          bfr[ni] = __builtin_bit_cast(bf16x8, ldsB[1][bbase + ni * 128 + ck]);
#pragma unroll
        for (int mi = 0; mi < 4; ++mi)
#pragma unroll
          for (int ni = 0; ni < 4; ++ni)
            acc[mi][ni] = __builtin_amdgcn_mfma_f32_16x16x32_bf16(af[mi], bfr[ni], acc[mi][ni], 0, 0, 0);
      }
#pragma unroll
      for (int j = 0; j < 4; ++j) {
        ldsA[0][t + j * 256] = sA0[j];
        ldsB[0][t + j * 256] = sB0[j];
      }
      LGKM_BARRIER();
    }
  }

  // Epilogue: C/D layout col=lane&15, row=(lane>>4)*4+reg
  const float* Ap = A + (size_t)g * S_N + bm + wm * 64;
  const float* Cp = C + (size_t)g * X_N + bn + wn * 64;
  float cv[4];
#pragma unroll
  for (int ni = 0; ni < 4; ++ni) cv[ni] = Cp[ni * 16 + r];
#pragma unroll
  for (int mi = 0; mi < 4; ++mi) {
#pragma unroll
    for (int i = 0; i < 4; ++i) {
      int rowl = wm * 64 + mi * 16 + q * 4 + i;
      float av = Ap[mi * 16 + q * 4 + i];
      float* orow = logits + ((size_t)g * S_N + bm + rowl) * X_N + bn + wn * 64;
#pragma unroll
      for (int ni = 0; ni < 4; ++ni)
        orow[ni * 16 + r] = acc[mi][ni][i] - 0.5f * (av + cv[ni]);
    }
  }
}

// ---------------- P2: out[s] = LSE over (g,x) of (logits + const[g]) - log(X*G)
__global__ void k_lse(const float* __restrict__ logits, const float* __restrict__ constg,
                      float* __restrict__ out) {
  int s = blockIdx.x, t = threadIdx.x;
  float c0 = constg[0], c1 = constg[1];
  const float4* p0 = (const float4*)(logits + (size_t)s * X_N);
  const float4* p1 = (const float4*)(logits + ((size_t)S_N + s) * X_N);
  float4 v[4];
  v[0] = p0[t]; v[1] = p0[t + 256];
  v[2] = p1[t]; v[3] = p1[t + 256];
  v[0].x += c0; v[0].y += c0; v[0].z += c0; v[0].w += c0;
  v[1].x += c0; v[1].y += c0; v[1].z += c0; v[1].w += c0;
  v[2].x += c1; v[2].y += c1; v[2].z += c1; v[2].w += c1;
  v[3].x += c1; v[3].y += c1; v[3].z += c1; v[3].w += c1;

  float m = v[0].x;
#pragma unroll
  for (int j = 0; j < 4; ++j) {
    m = fmaxf(m, v[j].x); m = fmaxf(m, v[j].y);
    m = fmaxf(m, v[j].z); m = fmaxf(m, v[j].w);
  }
  for (int o = 32; o; o >>= 1) m = fmaxf(m, __shfl_xor(m, o));
  __shared__ float redm[4];
  __shared__ float reds[4];
  int w = t >> 6, l = t & 63;
  if (l == 0) redm[w] = m;
  __syncthreads();
  m = fmaxf(fmaxf(redm[0], redm[1]), fmaxf(redm[2], redm[3]));

  float sum = 0.f;
#pragma unroll
  for (int j = 0; j < 4; ++j) {
    sum += expf(v[j].x - m) + expf(v[j].y - m) + expf(v[j].z - m) + expf(v[j].w - m);
  }
  for (int o = 32; o; o >>= 1) sum += __shfl_xor(sum, o);
  if (l == 0) reds[w] = sum;
  __syncthreads();
  if (t == 0) {
    float tot = reds[0] + reds[1] + reds[2] + reds[3];
    out[s] = m + logf(tot) - 8.317766166719343f;  // log(4096)
  }
}

extern "C" void kernel_launch(void* const* d_in, const int* in_sizes, int n_in,
                              void* d_out, int out_size, void* d_ws, size_t ws_size,
                              hipStream_t stream) {
  const float* samples = (const float*)d_in[0];  // [S, F] fp32
  const float* xin     = (const float*)d_in[1];  // [X, F] fp32
  const float* stdv    = (const float*)d_in[2];  // [G, F] fp32
  float* out = (float*)d_out;                    // [S] fp32

  char* ws = (char*)d_ws;
  size_t off = 0;
  bf16* U = (bf16*)(ws + off);        off += (size_t)G_N * S_N * F_N * 2;  // 25.2 MB
  bf16* V = (bf16*)(ws + off);        off += (size_t)G_N * X_N * F_N * 2;  // 25.2 MB
  float* logits = (float*)(ws + off); off += (size_t)G_N * S_N * X_N * 4;  // 33.6 MB
  float* A = (float*)(ws + off);      off += (size_t)G_N * S_N * 4;
  float* C = (float*)(ws + off);      off += (size_t)G_N * X_N * 4;
  float* constg = (float*)(ws + off); off += 256;
  float* rinv = (float*)(ws + off);   off += (size_t)G_N * F_N * 4;

  k_const<<<dim3(G_N), dim3(256), 0, stream>>>(stdv, constg, rinv);
  k_prep<<<dim3(S_N + X_N), dim3(256), 0, stream>>>(samples, xin, rinv, U, V, A, C);
  k_gemm<<<dim3(X_N / TN, S_N / TM, G_N), dim3(256), 0, stream>>>(U, V, A, C, logits);
  k_lse<<<dim3(S_N), dim3(256), 0, stream>>>(logits, constg, out);
}